// Round 5
// baseline (235.976 us; speedup 1.0000x reference)
//
#include <hip/hip_runtime.h>

#define CROP  14
#define POS   196
#define HH    200
#define WW    304
#define CC    256
#define NIMG  8
#define TR    25          // top-rows owned per tile
#define NT    8           // tiles per image
#define NBIN  (NIMG*NT)   // 64

// ws layout (bytes):
// [0,256):    u32 counts[64]
// [256,512):  u32 offsets[64]
// [512,768):  u32 cursors[64]
// [1024, 1024+196000*16): int4 desc[]   (3.14 MB total)
// desc: .x = offtl | dx<<13 | dy<<14 | valid<<15 ; .y = n*CC*POS + s ; .z = xl ; .w = yl

__device__ __forceinline__ int top_row(float y1, float y2, int yy) {
    const float in_y = y1*199.0f + (float)yy*((y2-y1)*199.0f*(1.0f/13.0f));
    return (int)fminf(fmaxf(floorf(in_y), 0.0f), 199.0f);
}

// ---- fused: zero counts + per-bin sample counts + exclusive scan (1 block) ----
__global__ __launch_bounds__(1024) void prep(
    const float* __restrict__ boxes, const int* __restrict__ bidx, int n_boxes,
    unsigned* __restrict__ counts, unsigned* __restrict__ offsets,
    unsigned* __restrict__ cursors)
{
    __shared__ unsigned scnt[NBIN];
    const int t = threadIdx.x;
    if (t < NBIN) scnt[t] = 0;
    __syncthreads();
    for (int n = t; n < n_boxes; n += 1024) {
        const float y1 = boxes[4*n+0], y2 = boxes[4*n+2];
        const int b = bidx[n];
        int prev = -1, yyLo = 0;
        for (int yy = 0; yy < 14; ++yy) {
            const int tile = top_row(y1, y2, yy) / TR;
            if (tile != prev) {
                if (prev >= 0) atomicAdd(&scnt[b*NT+prev], (unsigned)((yy-yyLo)*CROP));
                prev = tile; yyLo = yy;
            }
        }
        atomicAdd(&scnt[b*NT+prev], (unsigned)((14-yyLo)*CROP));
    }
    __syncthreads();
    if (t == 0) {
        unsigned acc = 0;
        for (int i = 0; i < NBIN; ++i) {
            const unsigned c = scnt[i];
            counts[i] = c; offsets[i] = acc; cursors[i] = acc; acc += c;
        }
    }
}

__global__ __launch_bounds__(256) void emit_desc(
    const float* __restrict__ boxes, const int* __restrict__ bidx,
    unsigned* __restrict__ cursors, int4* __restrict__ desc)
{
    __shared__ int rowSlot[14];
    const int n = blockIdx.x;
    const int t = threadIdx.x;
    const float y1 = boxes[4*n+0], x1 = boxes[4*n+1];
    const float y2 = boxes[4*n+2], x2 = boxes[4*n+3];
    const int b = bidx[n];

    if (t == 0) {
        int tiles[14];
        for (int yy = 0; yy < 14; ++yy) tiles[yy] = top_row(y1, y2, yy) / TR;
        for (int yy = 0; yy < 14; ++yy) {
            if (yy == 0 || tiles[yy] != tiles[yy-1]) {
                int hi = yy;
                while (hi+1 < 14 && tiles[hi+1] == tiles[yy]) ++hi;
                const unsigned base = atomicAdd(&cursors[b*NT + tiles[yy]],
                                                (unsigned)((hi-yy+1)*CROP));
                for (int r = yy; r <= hi; ++r) rowSlot[r] = (int)base + (r-yy)*CROP;
            }
        }
    }
    __syncthreads();

    if (t < POS) {
        const int yy = t / CROP, xx = t - yy*CROP;
        const float in_y = y1*199.0f + (float)yy*((y2-y1)*199.0f*(1.0f/13.0f));
        const float in_x = x1*303.0f + (float)xx*((x2-x1)*303.0f*(1.0f/13.0f));
        const float tf = floorf(in_y), lf = floorf(in_x);
        const int topc   = (int)fminf(fmaxf(tf,          0.0f), 199.0f);
        const int botc   = (int)fminf(fmaxf(ceilf(in_y), 0.0f), 199.0f);
        const int leftc  = (int)fminf(fmaxf(lf,          0.0f), 303.0f);
        const int rightc = (int)fminf(fmaxf(ceilf(in_x), 0.0f), 303.0f);
        const int tile = topc / TR;
        const int r0   = topc - tile*TR;
        const unsigned w0 = (unsigned)(r0*WW + leftc)
                          | ((unsigned)(rightc - leftc) << 13)
                          | ((unsigned)(botc - topc)    << 14)
                          | ((unsigned)((in_y >= 0.0f) & (in_y <= 199.0f) &
                                        (in_x >= 0.0f) & (in_x <= 303.0f)) << 15);
        int4 d;
        d.x = (int)w0;
        d.y = n*CC*POS + t;
        d.z = __float_as_int(in_x - lf);
        d.w = __float_as_int(in_y - tf);
        desc[rowSlot[yy] + xx] = d;
    }
}

__global__ __launch_bounds__(512) void crop_compute(
    const float*    __restrict__ image,
    const unsigned* __restrict__ counts,
    const unsigned* __restrict__ offsets,
    const int4*     __restrict__ desc,
    float*          __restrict__ out)
{
    __shared__ float tile[26 * WW];        // 31,616 B -> 4 blocks/CU, 32 waves
    const int c   = blockIdx.x;
    const int bin = blockIdx.y;
    const int b   = bin >> 3;
    const int tl  = bin & 7;
    const int t   = threadIdx.x;
    const int base = tl * TR;
    const int rows = (tl == NT-1) ? TR : TR + 1;

    const int S    = (int)counts[bin];
    const int off0 = (int)offsets[bin];

    {
        const float* src = image + ((size_t)b*CC + (size_t)c)*(size_t)(HH*WW)
                                 + (size_t)base*WW;
        const int nv = (rows * WW) >> 2;
        const float4* s4 = (const float4*)src;
        float4* t4 = (float4*)tile;
        for (int i = t; i < nv; i += 512) t4[i] = s4[i];
    }
    __syncthreads();
    if (S == 0) return;

    const size_t cbase = (size_t)c * POS;

    // depth-2 software pipeline on the desc stream: next iteration's 16B
    // descriptor load is issued before this iteration's LDS gathers.
    int k = t;
    int4 d = (k < S) ? desc[off0 + k] : make_int4(0,0,0,0);
    while (k < S) {
        const int kn = k + 512;
        int4 dn;
        if (kn < S) dn = desc[off0 + kn];

        const unsigned w0 = (unsigned)d.x;
        const int off = (int)(w0 & 0x1FFFu);
        const int dx  = (int)((w0 >> 13) & 1u);
        const int dyw = ((w0 >> 14) & 1u) ? WW : 0;
        const float xl = __int_as_float(d.z);
        const float yl = __int_as_float(d.w);
        const float tlv = tile[off];
        const float trv = tile[off + dx];
        const float blv = tile[off + dyw];
        const float brv = tile[off + dyw + dx];
        const float tv = tlv + (trv - tlv) * xl;
        const float bv = blv + (brv - blv) * xl;
        float v = tv + (bv - tv) * yl;
        v = (w0 & 0x8000u) ? v : 0.0f;
        __builtin_nontemporal_store(v, &out[(size_t)(unsigned)d.y + cbase]);

        k = kn; d = dn;
    }
}

extern "C" void kernel_launch(void* const* d_in, const int* in_sizes, int n_in,
                              void* d_out, int out_size, void* d_ws, size_t ws_size,
                              hipStream_t stream) {
    const float* image = (const float*)d_in[0];
    const float* boxes = (const float*)d_in[1];
    const int*   bidx  = (const int*)d_in[2];
    float*       out   = (float*)d_out;
    const int n_boxes = in_sizes[1] / 4;     // 1000

    unsigned* counts  = (unsigned*)d_ws;
    unsigned* offsets = counts + 64;
    unsigned* cursors = counts + 128;
    int4*     desc    = (int4*)((char*)d_ws + 1024);

    prep<<<dim3(1), dim3(1024), 0, stream>>>(boxes, bidx, n_boxes, counts, offsets, cursors);
    emit_desc<<<dim3(n_boxes), dim3(256), 0, stream>>>(boxes, bidx, cursors, desc);
    crop_compute<<<dim3(CC, NBIN), dim3(512), 0, stream>>>(image, counts, offsets, desc, out);
}

// Round 6
// 199.727 us; speedup vs baseline: 1.1815x; 1.1815x over previous
//
#include <hip/hip_runtime.h>

#define CROP  14
#define POS   196
#define HH    200
#define WW    304
#define CC    256
#define NIMG  8
#define TR    25          // top-rows owned per tile
#define NT    8           // tiles per image
#define NBIN  (NIMG*NT)   // 64
#define TSZ   (26*WW)     // floats per plane tile (7904)

// ws layout (bytes):
// [0,256):    u32 counts[64]
// [256,512):  u32 offsets[64]
// [512,768):  u32 cursors[64]
// [1024, 1024+196000*16): int4 desc[]
// desc: .x = offtl | dx<<13 | dy<<14 | valid<<15 ; .y = n*CC*POS + s ; .z = xl ; .w = yl

__device__ __forceinline__ int top_row(float y1, float y2, int yy) {
    const float in_y = y1*199.0f + (float)yy*((y2-y1)*199.0f*(1.0f/13.0f));
    return (int)fminf(fmaxf(floorf(in_y), 0.0f), 199.0f);
}

// ---- fused: zero counts + per-bin sample counts + exclusive scan (1 block) ----
__global__ __launch_bounds__(1024) void prep(
    const float* __restrict__ boxes, const int* __restrict__ bidx, int n_boxes,
    unsigned* __restrict__ counts, unsigned* __restrict__ offsets,
    unsigned* __restrict__ cursors)
{
    __shared__ unsigned scnt[NBIN];
    const int t = threadIdx.x;
    if (t < NBIN) scnt[t] = 0;
    __syncthreads();
    for (int n = t; n < n_boxes; n += 1024) {
        const float y1 = boxes[4*n+0], y2 = boxes[4*n+2];
        const int b = bidx[n];
        int prev = -1, yyLo = 0;
        for (int yy = 0; yy < 14; ++yy) {
            const int tile = top_row(y1, y2, yy) / TR;
            if (tile != prev) {
                if (prev >= 0) atomicAdd(&scnt[b*NT+prev], (unsigned)((yy-yyLo)*CROP));
                prev = tile; yyLo = yy;
            }
        }
        atomicAdd(&scnt[b*NT+prev], (unsigned)((14-yyLo)*CROP));
    }
    __syncthreads();
    if (t == 0) {
        unsigned acc = 0;
        for (int i = 0; i < NBIN; ++i) {
            const unsigned c = scnt[i];
            counts[i] = c; offsets[i] = acc; cursors[i] = acc; acc += c;
        }
    }
}

__global__ __launch_bounds__(256) void emit_desc(
    const float* __restrict__ boxes, const int* __restrict__ bidx,
    unsigned* __restrict__ cursors, int4* __restrict__ desc)
{
    __shared__ int rowSlot[14];
    const int n = blockIdx.x;
    const int t = threadIdx.x;
    const float y1 = boxes[4*n+0], x1 = boxes[4*n+1];
    const float y2 = boxes[4*n+2], x2 = boxes[4*n+3];
    const int b = bidx[n];

    if (t == 0) {
        int tiles[14];
        for (int yy = 0; yy < 14; ++yy) tiles[yy] = top_row(y1, y2, yy) / TR;
        for (int yy = 0; yy < 14; ++yy) {
            if (yy == 0 || tiles[yy] != tiles[yy-1]) {
                int hi = yy;
                while (hi+1 < 14 && tiles[hi+1] == tiles[yy]) ++hi;
                const unsigned base = atomicAdd(&cursors[b*NT + tiles[yy]],
                                                (unsigned)((hi-yy+1)*CROP));
                for (int r = yy; r <= hi; ++r) rowSlot[r] = (int)base + (r-yy)*CROP;
            }
        }
    }
    __syncthreads();

    if (t < POS) {
        const int yy = t / CROP, xx = t - yy*CROP;
        const float in_y = y1*199.0f + (float)yy*((y2-y1)*199.0f*(1.0f/13.0f));
        const float in_x = x1*303.0f + (float)xx*((x2-x1)*303.0f*(1.0f/13.0f));
        const float tf = floorf(in_y), lf = floorf(in_x);
        const int topc   = (int)fminf(fmaxf(tf,          0.0f), 199.0f);
        const int botc   = (int)fminf(fmaxf(ceilf(in_y), 0.0f), 199.0f);
        const int leftc  = (int)fminf(fmaxf(lf,          0.0f), 303.0f);
        const int rightc = (int)fminf(fmaxf(ceilf(in_x), 0.0f), 303.0f);
        const int tile = topc / TR;
        const int r0   = topc - tile*TR;
        const unsigned w0 = (unsigned)(r0*WW + leftc)
                          | ((unsigned)(rightc - leftc) << 13)
                          | ((unsigned)(botc - topc)    << 14)
                          | ((unsigned)((in_y >= 0.0f) & (in_y <= 199.0f) &
                                        (in_x >= 0.0f) & (in_x <= 303.0f)) << 15);
        int4 d;
        d.x = (int)w0;
        d.y = n*CC*POS + t;
        d.z = __float_as_int(in_x - lf);
        d.w = __float_as_int(in_y - tf);
        desc[rowSlot[yy] + xx] = d;
    }
}

// 2 channels per block: one desc read serves both planes.
__global__ __launch_bounds__(512) void crop_compute(
    const float*    __restrict__ image,
    const unsigned* __restrict__ counts,
    const unsigned* __restrict__ offsets,
    const int4*     __restrict__ desc,
    float*          __restrict__ out)
{
    __shared__ float tile[2 * TSZ];        // 63,232 B -> 2 blocks/CU
    const int c0  = blockIdx.x * 2;
    const int bin = blockIdx.y;
    const int b   = bin >> 3;
    const int tl  = bin & 7;
    const int t   = threadIdx.x;
    const int base = tl * TR;
    const int rows = (tl == NT-1) ? TR : TR + 1;

    const int S    = (int)counts[bin];
    const int off0 = (int)offsets[bin];

    {
        const float* src = image + ((size_t)b*CC + (size_t)c0)*(size_t)(HH*WW)
                                 + (size_t)base*WW;
        const int nv = (rows * WW) >> 2;           // per plane
        const float4* s4a = (const float4*)src;
        const float4* s4b = (const float4*)(src + HH*WW);
        float4* t4a = (float4*)tile;
        float4* t4b = (float4*)(tile + TSZ);
        for (int i = t; i < nv; i += 512) { t4a[i] = s4a[i]; t4b[i] = s4b[i]; }
    }
    __syncthreads();
    if (S == 0) return;

    const size_t cb0 = (size_t)c0 * POS;
    for (int k = t; k < S; k += 512) {
        const int4 d = desc[off0 + k];
        const unsigned w0 = (unsigned)d.x;
        const int off = (int)(w0 & 0x1FFFu);
        const int dx  = (int)((w0 >> 13) & 1u);
        const int dyw = ((w0 >> 14) & 1u) ? WW : 0;
        const float xl = __int_as_float(d.z);
        const float yl = __int_as_float(d.w);

        const float* p0 = tile + off;
        const float* p1 = p0 + TSZ;
        const float tl0 = p0[0];
        const float tr0 = p0[dx];
        const float bl0 = p0[dyw];
        const float br0 = p0[dyw + dx];
        const float tl1 = p1[0];
        const float tr1 = p1[dx];
        const float bl1 = p1[dyw];
        const float br1 = p1[dyw + dx];

        const float tv0 = tl0 + (tr0 - tl0) * xl;
        const float bv0 = bl0 + (br0 - bl0) * xl;
        const float tv1 = tl1 + (tr1 - tl1) * xl;
        const float bv1 = bl1 + (br1 - bl1) * xl;
        float v0 = tv0 + (bv0 - tv0) * yl;
        float v1 = tv1 + (bv1 - tv1) * yl;
        if (!(w0 & 0x8000u)) { v0 = 0.0f; v1 = 0.0f; }

        const size_t o = (size_t)(unsigned)d.y + cb0;
        out[o]       = v0;
        out[o + POS] = v1;
    }
}

extern "C" void kernel_launch(void* const* d_in, const int* in_sizes, int n_in,
                              void* d_out, int out_size, void* d_ws, size_t ws_size,
                              hipStream_t stream) {
    const float* image = (const float*)d_in[0];
    const float* boxes = (const float*)d_in[1];
    const int*   bidx  = (const int*)d_in[2];
    float*       out   = (float*)d_out;
    const int n_boxes = in_sizes[1] / 4;     // 1000

    unsigned* counts  = (unsigned*)d_ws;
    unsigned* offsets = counts + 64;
    unsigned* cursors = counts + 128;
    int4*     desc    = (int4*)((char*)d_ws + 1024);

    prep<<<dim3(1), dim3(1024), 0, stream>>>(boxes, bidx, n_boxes, counts, offsets, cursors);
    emit_desc<<<dim3(n_boxes), dim3(256), 0, stream>>>(boxes, bidx, cursors, desc);
    crop_compute<<<dim3(CC/2, NBIN), dim3(512), 0, stream>>>(image, counts, offsets, desc, out);
}

// Round 7
// 187.402 us; speedup vs baseline: 1.2592x; 1.0658x over previous
//
#include <hip/hip_runtime.h>

#define CROP  14
#define POS   196
#define HH    200
#define WW    304
#define CC    256
#define NIMG  8
#define TR    13          // top-rows owned per tile
#define NT    16          // tiles per image (16*13=208 >= 200)
#define NBIN  (NIMG*NT)   // 128
#define TSZ   (14*WW)     // floats per plane tile (4256)

// ws layout (bytes):
// [0,512):     u32 counts[128]
// [512,1024):  u32 offsets[128]
// [1024,1536): u32 cursors[128]
// [2048, 2048+196000*16): int4 desc[]
// desc: .x = offtl | dx<<13 | dy<<14 | valid<<15 ; .y = n*CC*POS + s ; .z = xl ; .w = yl

__device__ __forceinline__ int top_row(float y1, float y2, int yy) {
    const float in_y = y1*199.0f + (float)yy*((y2-y1)*199.0f*(1.0f/13.0f));
    return (int)fminf(fmaxf(floorf(in_y), 0.0f), 199.0f);
}

// ---- fused: zero counts + per-bin sample counts + exclusive scan (1 block) ----
__global__ __launch_bounds__(1024) void prep(
    const float* __restrict__ boxes, const int* __restrict__ bidx, int n_boxes,
    unsigned* __restrict__ counts, unsigned* __restrict__ offsets,
    unsigned* __restrict__ cursors)
{
    __shared__ unsigned scnt[NBIN];
    const int t = threadIdx.x;
    if (t < NBIN) scnt[t] = 0;
    __syncthreads();
    for (int n = t; n < n_boxes; n += 1024) {
        const float y1 = boxes[4*n+0], y2 = boxes[4*n+2];
        const int b = bidx[n];
        int prev = -1, yyLo = 0;
        for (int yy = 0; yy < 14; ++yy) {
            const int tile = top_row(y1, y2, yy) / TR;
            if (tile != prev) {
                if (prev >= 0) atomicAdd(&scnt[b*NT+prev], (unsigned)((yy-yyLo)*CROP));
                prev = tile; yyLo = yy;
            }
        }
        atomicAdd(&scnt[b*NT+prev], (unsigned)((14-yyLo)*CROP));
    }
    __syncthreads();
    if (t == 0) {
        unsigned acc = 0;
        for (int i = 0; i < NBIN; ++i) {
            const unsigned c = scnt[i];
            counts[i] = c; offsets[i] = acc; cursors[i] = acc; acc += c;
        }
    }
}

__global__ __launch_bounds__(256) void emit_desc(
    const float* __restrict__ boxes, const int* __restrict__ bidx,
    unsigned* __restrict__ cursors, int4* __restrict__ desc)
{
    __shared__ int rowSlot[14];
    const int n = blockIdx.x;
    const int t = threadIdx.x;
    const float y1 = boxes[4*n+0], x1 = boxes[4*n+1];
    const float y2 = boxes[4*n+2], x2 = boxes[4*n+3];
    const int b = bidx[n];

    if (t == 0) {
        int tiles[14];
        for (int yy = 0; yy < 14; ++yy) tiles[yy] = top_row(y1, y2, yy) / TR;
        for (int yy = 0; yy < 14; ++yy) {
            if (yy == 0 || tiles[yy] != tiles[yy-1]) {
                int hi = yy;
                while (hi+1 < 14 && tiles[hi+1] == tiles[yy]) ++hi;
                const unsigned base = atomicAdd(&cursors[b*NT + tiles[yy]],
                                                (unsigned)((hi-yy+1)*CROP));
                for (int r = yy; r <= hi; ++r) rowSlot[r] = (int)base + (r-yy)*CROP;
            }
        }
    }
    __syncthreads();

    if (t < POS) {
        const int yy = t / CROP, xx = t - yy*CROP;
        const float in_y = y1*199.0f + (float)yy*((y2-y1)*199.0f*(1.0f/13.0f));
        const float in_x = x1*303.0f + (float)xx*((x2-x1)*303.0f*(1.0f/13.0f));
        const float tf = floorf(in_y), lf = floorf(in_x);
        const int topc   = (int)fminf(fmaxf(tf,          0.0f), 199.0f);
        const int botc   = (int)fminf(fmaxf(ceilf(in_y), 0.0f), 199.0f);
        const int leftc  = (int)fminf(fmaxf(lf,          0.0f), 303.0f);
        const int rightc = (int)fminf(fmaxf(ceilf(in_x), 0.0f), 303.0f);
        const int tile = topc / TR;
        const int r0   = topc - tile*TR;          // 0..12, bot row r0+1 <= 13
        const unsigned w0 = (unsigned)(r0*WW + leftc)
                          | ((unsigned)(rightc - leftc) << 13)
                          | ((unsigned)(botc - topc)    << 14)
                          | ((unsigned)((in_y >= 0.0f) & (in_y <= 199.0f) &
                                        (in_x >= 0.0f) & (in_x <= 303.0f)) << 15);
        int4 d;
        d.x = (int)w0;
        d.y = n*CC*POS + t;
        d.z = __float_as_int(in_x - lf);
        d.w = __float_as_int(in_y - tf);
        desc[rowSlot[yy] + xx] = d;
    }
}

// 4 channels per block: one desc read serves four planes.
__global__ __launch_bounds__(512) void crop_compute(
    const float*    __restrict__ image,
    const unsigned* __restrict__ counts,
    const unsigned* __restrict__ offsets,
    const int4*     __restrict__ desc,
    float*          __restrict__ out)
{
    __shared__ float tile[4 * TSZ];        // 68,096 B -> 2 blocks/CU
    const int c0  = blockIdx.x * 4;
    const int bin = blockIdx.y;
    const int b   = bin >> 4;              // bin / NT
    const int tl  = bin & 15;              // bin % NT
    const int t   = threadIdx.x;
    const int base = tl * TR;
    const int rows = (tl == NT-1) ? (HH - (NT-1)*TR) : (TR + 1);  // 5 or 14

    const int S    = (int)counts[bin];
    const int off0 = (int)offsets[bin];

    {
        const float* src = image + ((size_t)b*CC + (size_t)c0)*(size_t)(HH*WW)
                                 + (size_t)base*WW;
        const int nv = (rows * WW) >> 2;   // per plane (380 or 1064)
        const float4* s4a = (const float4*)src;
        const float4* s4b = (const float4*)(src +     HH*WW);
        const float4* s4c = (const float4*)(src + 2 * HH*WW);
        const float4* s4d = (const float4*)(src + 3 * HH*WW);
        float4* t4a = (float4*)tile;
        float4* t4b = (float4*)(tile +     TSZ);
        float4* t4c = (float4*)(tile + 2 * TSZ);
        float4* t4d = (float4*)(tile + 3 * TSZ);
        for (int i = t; i < nv; i += 512) {
            t4a[i] = s4a[i]; t4b[i] = s4b[i]; t4c[i] = s4c[i]; t4d[i] = s4d[i];
        }
    }
    __syncthreads();
    if (S == 0) return;

    const size_t cb0 = (size_t)c0 * POS;
    for (int k = t; k < S; k += 512) {
        const int4 d = desc[off0 + k];
        const unsigned w0 = (unsigned)d.x;
        const int off = (int)(w0 & 0x1FFFu);
        const int dx  = (int)((w0 >> 13) & 1u);
        const int dyw = ((w0 >> 14) & 1u) ? WW : 0;
        const float xl = __int_as_float(d.z);
        const float yl = __int_as_float(d.w);

        const float* p0 = tile + off;
        const float* p1 = p0 + TSZ;
        const float* p2 = p0 + 2*TSZ;
        const float* p3 = p0 + 3*TSZ;

        const float tl0 = p0[0],  tr0 = p0[dx], bl0 = p0[dyw], br0 = p0[dyw+dx];
        const float tl1 = p1[0],  tr1 = p1[dx], bl1 = p1[dyw], br1 = p1[dyw+dx];
        const float tl2 = p2[0],  tr2 = p2[dx], bl2 = p2[dyw], br2 = p2[dyw+dx];
        const float tl3 = p3[0],  tr3 = p3[dx], bl3 = p3[dyw], br3 = p3[dyw+dx];

        const float tv0 = tl0 + (tr0 - tl0) * xl;
        const float bv0 = bl0 + (br0 - bl0) * xl;
        const float tv1 = tl1 + (tr1 - tl1) * xl;
        const float bv1 = bl1 + (br1 - bl1) * xl;
        const float tv2 = tl2 + (tr2 - tl2) * xl;
        const float bv2 = bl2 + (br2 - bl2) * xl;
        const float tv3 = tl3 + (tr3 - tl3) * xl;
        const float bv3 = bl3 + (br3 - bl3) * xl;

        float v0 = tv0 + (bv0 - tv0) * yl;
        float v1 = tv1 + (bv1 - tv1) * yl;
        float v2 = tv2 + (bv2 - tv2) * yl;
        float v3 = tv3 + (bv3 - tv3) * yl;
        if (!(w0 & 0x8000u)) { v0 = 0.0f; v1 = 0.0f; v2 = 0.0f; v3 = 0.0f; }

        const size_t o = (size_t)(unsigned)d.y + cb0;
        out[o]         = v0;
        out[o +   POS] = v1;
        out[o + 2*POS] = v2;
        out[o + 3*POS] = v3;
    }
}

extern "C" void kernel_launch(void* const* d_in, const int* in_sizes, int n_in,
                              void* d_out, int out_size, void* d_ws, size_t ws_size,
                              hipStream_t stream) {
    const float* image = (const float*)d_in[0];
    const float* boxes = (const float*)d_in[1];
    const int*   bidx  = (const int*)d_in[2];
    float*       out   = (float*)d_out;
    const int n_boxes = in_sizes[1] / 4;     // 1000

    unsigned* counts  = (unsigned*)d_ws;
    unsigned* offsets = counts + 128;
    unsigned* cursors = counts + 256;
    int4*     desc    = (int4*)((char*)d_ws + 2048);

    prep<<<dim3(1), dim3(1024), 0, stream>>>(boxes, bidx, n_boxes, counts, offsets, cursors);
    emit_desc<<<dim3(n_boxes), dim3(256), 0, stream>>>(boxes, bidx, cursors, desc);
    crop_compute<<<dim3(CC/4, NBIN), dim3(512), 0, stream>>>(image, counts, offsets, desc, out);
}

// Round 8
// 186.318 us; speedup vs baseline: 1.2665x; 1.0058x over previous
//
#include <hip/hip_runtime.h>

#define CROP  14
#define POS   196
#define HH    200
#define WW    304
#define CC    256
#define NIMG  8
#define TR    6           // top-rows owned per tile
#define NT    34          // tiles per image (34*6=204 >= 200)
#define NBIN  (NIMG*NT)   // 272
#define TSZ   (7*WW)      // floats per plane tile (2128)

// ws layout (u32 indices from base):
// counts[272], offsets[272], cursors[272], then desc (int4) at byte 4096
// desc: .x = offtl | dx<<13 | dy<<14 | valid<<15 ; .y = n*CC*POS + s ; .z = xl ; .w = yl

__device__ __forceinline__ int top_row(float y1, float y2, int yy) {
    const float in_y = y1*199.0f + (float)yy*((y2-y1)*199.0f*(1.0f/13.0f));
    return (int)fminf(fmaxf(floorf(in_y), 0.0f), 199.0f);
}

// ---- fused: zero counts + per-bin sample counts + exclusive scan (1 block) ----
__global__ __launch_bounds__(1024) void prep(
    const float* __restrict__ boxes, const int* __restrict__ bidx, int n_boxes,
    unsigned* __restrict__ counts, unsigned* __restrict__ offsets,
    unsigned* __restrict__ cursors)
{
    __shared__ unsigned scnt[NBIN];
    const int t = threadIdx.x;
    if (t < NBIN) scnt[t] = 0;
    __syncthreads();
    for (int n = t; n < n_boxes; n += 1024) {
        const float y1 = boxes[4*n+0], y2 = boxes[4*n+2];
        const int b = bidx[n];
        int prev = -1, yyLo = 0;
        for (int yy = 0; yy < 14; ++yy) {
            const int tile = top_row(y1, y2, yy) / TR;
            if (tile != prev) {
                if (prev >= 0) atomicAdd(&scnt[b*NT+prev], (unsigned)((yy-yyLo)*CROP));
                prev = tile; yyLo = yy;
            }
        }
        atomicAdd(&scnt[b*NT+prev], (unsigned)((14-yyLo)*CROP));
    }
    __syncthreads();
    if (t == 0) {
        unsigned acc = 0;
        for (int i = 0; i < NBIN; ++i) {
            const unsigned c = scnt[i];
            counts[i] = c; offsets[i] = acc; cursors[i] = acc; acc += c;
        }
    }
}

__global__ __launch_bounds__(256) void emit_desc(
    const float* __restrict__ boxes, const int* __restrict__ bidx,
    unsigned* __restrict__ cursors, int4* __restrict__ desc)
{
    __shared__ int rowSlot[14];
    const int n = blockIdx.x;
    const int t = threadIdx.x;
    const float y1 = boxes[4*n+0], x1 = boxes[4*n+1];
    const float y2 = boxes[4*n+2], x2 = boxes[4*n+3];
    const int b = bidx[n];

    if (t == 0) {
        int tiles[14];
        for (int yy = 0; yy < 14; ++yy) tiles[yy] = top_row(y1, y2, yy) / TR;
        for (int yy = 0; yy < 14; ++yy) {
            if (yy == 0 || tiles[yy] != tiles[yy-1]) {
                int hi = yy;
                while (hi+1 < 14 && tiles[hi+1] == tiles[yy]) ++hi;
                const unsigned base = atomicAdd(&cursors[b*NT + tiles[yy]],
                                                (unsigned)((hi-yy+1)*CROP));
                for (int r = yy; r <= hi; ++r) rowSlot[r] = (int)base + (r-yy)*CROP;
            }
        }
    }
    __syncthreads();

    if (t < POS) {
        const int yy = t / CROP, xx = t - yy*CROP;
        const float in_y = y1*199.0f + (float)yy*((y2-y1)*199.0f*(1.0f/13.0f));
        const float in_x = x1*303.0f + (float)xx*((x2-x1)*303.0f*(1.0f/13.0f));
        const float tf = floorf(in_y), lf = floorf(in_x);
        const int topc   = (int)fminf(fmaxf(tf,          0.0f), 199.0f);
        const int botc   = (int)fminf(fmaxf(ceilf(in_y), 0.0f), 199.0f);
        const int leftc  = (int)fminf(fmaxf(lf,          0.0f), 303.0f);
        const int rightc = (int)fminf(fmaxf(ceilf(in_x), 0.0f), 303.0f);
        const int tile = topc / TR;
        const int r0   = topc - tile*TR;          // 0..5 ; off <= 5*304+303 < 8192
        const unsigned w0 = (unsigned)(r0*WW + leftc)
                          | ((unsigned)(rightc - leftc) << 13)
                          | ((unsigned)(botc - topc)    << 14)
                          | ((unsigned)((in_y >= 0.0f) & (in_y <= 199.0f) &
                                        (in_x >= 0.0f) & (in_x <= 303.0f)) << 15);
        int4 d;
        d.x = (int)w0;
        d.y = n*CC*POS + t;
        d.z = __float_as_int(in_x - lf);
        d.w = __float_as_int(in_y - tf);
        desc[rowSlot[yy] + xx] = d;
    }
}

// 4 channels per block; 34 KB LDS -> 4 blocks/CU for fine-grained
// stage/compute interleave across blocks.
__global__ __launch_bounds__(512) void crop_compute(
    const float*    __restrict__ image,
    const unsigned* __restrict__ counts,
    const unsigned* __restrict__ offsets,
    const int4*     __restrict__ desc,
    float*          __restrict__ out)
{
    __shared__ float tile[4 * TSZ];        // 34,048 B
    const int c0  = blockIdx.x * 4;
    const int bin = blockIdx.y;
    const int b   = bin / NT;
    const int tl  = bin - b * NT;
    const int t   = threadIdx.x;
    const int base = tl * TR;
    const int rows = (tl == NT-1) ? (HH - (NT-1)*TR) : (TR + 1);  // 2 or 7

    const int S    = (int)counts[bin];
    const int off0 = (int)offsets[bin];

    {
        const float* src = image + ((size_t)b*CC + (size_t)c0)*(size_t)(HH*WW)
                                 + (size_t)base*WW;
        const int nv = (rows * WW) >> 2;   // per plane (152 or 532)
        const float4* s4a = (const float4*)src;
        const float4* s4b = (const float4*)(src +     HH*WW);
        const float4* s4c = (const float4*)(src + 2 * HH*WW);
        const float4* s4d = (const float4*)(src + 3 * HH*WW);
        float4* t4a = (float4*)tile;
        float4* t4b = (float4*)(tile +     TSZ);
        float4* t4c = (float4*)(tile + 2 * TSZ);
        float4* t4d = (float4*)(tile + 3 * TSZ);
        for (int i = t; i < nv; i += 512) {
            t4a[i] = s4a[i]; t4b[i] = s4b[i]; t4c[i] = s4c[i]; t4d[i] = s4d[i];
        }
    }
    __syncthreads();
    if (S == 0) return;

    const size_t cb0 = (size_t)c0 * POS;
    for (int k = t; k < S; k += 512) {
        const int4 d = desc[off0 + k];
        const unsigned w0 = (unsigned)d.x;
        const int off = (int)(w0 & 0x1FFFu);
        const int dx  = (int)((w0 >> 13) & 1u);
        const int dyw = ((w0 >> 14) & 1u) ? WW : 0;
        const float xl = __int_as_float(d.z);
        const float yl = __int_as_float(d.w);

        const float* p0 = tile + off;
        const float* p1 = p0 + TSZ;
        const float* p2 = p0 + 2*TSZ;
        const float* p3 = p0 + 3*TSZ;

        const float tl0 = p0[0],  tr0 = p0[dx], bl0 = p0[dyw], br0 = p0[dyw+dx];
        const float tl1 = p1[0],  tr1 = p1[dx], bl1 = p1[dyw], br1 = p1[dyw+dx];
        const float tl2 = p2[0],  tr2 = p2[dx], bl2 = p2[dyw], br2 = p2[dyw+dx];
        const float tl3 = p3[0],  tr3 = p3[dx], bl3 = p3[dyw], br3 = p3[dyw+dx];

        const float tv0 = tl0 + (tr0 - tl0) * xl;
        const float bv0 = bl0 + (br0 - bl0) * xl;
        const float tv1 = tl1 + (tr1 - tl1) * xl;
        const float bv1 = bl1 + (br1 - bl1) * xl;
        const float tv2 = tl2 + (tr2 - tl2) * xl;
        const float bv2 = bl2 + (br2 - bl2) * xl;
        const float tv3 = tl3 + (tr3 - tl3) * xl;
        const float bv3 = bl3 + (br3 - bl3) * xl;

        float v0 = tv0 + (bv0 - tv0) * yl;
        float v1 = tv1 + (bv1 - tv1) * yl;
        float v2 = tv2 + (bv2 - tv2) * yl;
        float v3 = tv3 + (bv3 - tv3) * yl;
        if (!(w0 & 0x8000u)) { v0 = 0.0f; v1 = 0.0f; v2 = 0.0f; v3 = 0.0f; }

        const size_t o = (size_t)(unsigned)d.y + cb0;
        out[o]         = v0;
        out[o +   POS] = v1;
        out[o + 2*POS] = v2;
        out[o + 3*POS] = v3;
    }
}

extern "C" void kernel_launch(void* const* d_in, const int* in_sizes, int n_in,
                              void* d_out, int out_size, void* d_ws, size_t ws_size,
                              hipStream_t stream) {
    const float* image = (const float*)d_in[0];
    const float* boxes = (const float*)d_in[1];
    const int*   bidx  = (const int*)d_in[2];
    float*       out   = (float*)d_out;
    const int n_boxes = in_sizes[1] / 4;     // 1000

    unsigned* counts  = (unsigned*)d_ws;
    unsigned* offsets = counts + NBIN;
    unsigned* cursors = counts + 2*NBIN;
    int4*     desc    = (int4*)((char*)d_ws + 4096);

    prep<<<dim3(1), dim3(1024), 0, stream>>>(boxes, bidx, n_boxes, counts, offsets, cursors);
    emit_desc<<<dim3(n_boxes), dim3(256), 0, stream>>>(boxes, bidx, cursors, desc);
    crop_compute<<<dim3(CC/4, NBIN), dim3(512), 0, stream>>>(image, counts, offsets, desc, out);
}